// Round 9
// baseline (445.867 us; speedup 1.0000x reference)
//
#include <hip/hip_runtime.h>
#include <hip/hip_bf16.h>

#define B_   1024
#define L_   200
#define H_   128
#define BL_  204800   // B_*L_
#define G3_  384

typedef __bf16 bf16x8 __attribute__((ext_vector_type(8)));
typedef __bf16 bf16x4 __attribute__((ext_vector_type(4)));
typedef float  f32x4  __attribute__((ext_vector_type(4)));

__device__ __forceinline__ float sigf(float x) {
    return __builtin_amdgcn_rcpf(1.f + __expf(-x));
}
__device__ __forceinline__ float tanh_fast(float x) {
    float e = __expf(-2.f * x);
    return (1.f - e) * __builtin_amdgcn_rcpf(1.f + e);
}
__device__ __forceinline__ bf16x8 cvt8(float4 a, float4 b) {
    bf16x8 v;
    v[0] = (__bf16)a.x; v[1] = (__bf16)a.y; v[2] = (__bf16)a.z; v[3] = (__bf16)a.w;
    v[4] = (__bf16)b.x; v[5] = (__bf16)b.y; v[6] = (__bf16)b.z; v[7] = (__bf16)b.w;
    return v;
}
// LDS-only barrier: waits ds-ops (lgkmcnt) but does NOT drain vmcnt — global
// prefetch loads / result stores stay in flight across steps.
__device__ __forceinline__ void barrier_lds() {
    __builtin_amdgcn_sched_barrier(0);
    asm volatile("s_waitcnt lgkmcnt(0)" ::: "memory");
    __builtin_amdgcn_s_barrier();
    __builtin_amdgcn_sched_barrier(0);
}
// 16-lane sum via DPP row_ror adds (VALU pipe) — all lanes get the sum.
__device__ __forceinline__ float red16(float v) {
    v += __int_as_float(__builtin_amdgcn_update_dpp(0, __float_as_int(v), 0x121, 0xF, 0xF, true)); // ror:1
    v += __int_as_float(__builtin_amdgcn_update_dpp(0, __float_as_int(v), 0x122, 0xF, 0xF, true)); // ror:2
    v += __int_as_float(__builtin_amdgcn_update_dpp(0, __float_as_int(v), 0x124, 0xF, 0xF, true)); // ror:4
    v += __int_as_float(__builtin_amdgcn_update_dpp(0, __float_as_int(v), 0x128, 0xF, 0xF, true)); // ror:8
    return v;
}

// ---------------- K0: sentinel (workspace too small -> distinguishable absmax)
__global__ __launch_bounds__(256) void k_sentinel(float* __restrict__ out, int n) {
    const int i = blockIdx.x * 256 + threadIdx.x;
    if (i < n) out[i] = -5.0f;
}

// ---------------- K1: dec_linear
__global__ __launch_bounds__(256) void k_declin(
    const float* __restrict__ rcv, const float* __restrict__ Wl,
    const float* __restrict__ bl, float* __restrict__ code) {
    __shared__ float rs[4][400];
    const int tid = threadIdx.x;
    const int b0 = blockIdx.x * 4;
    for (int i = tid; i < 1600; i += 256) ((float*)rs)[i] = rcv[(size_t)b0 * 400 + i];
    __syncthreads();
    #pragma unroll
    for (int rep = 0; rep < 2; ++rep) {
        const int j = tid + rep * 256;
        if (j < 400) {
            float a0 = 0.f, a1 = 0.f, a2 = 0.f, a3 = 0.f;
            const float4* wp = (const float4*)(Wl + (size_t)j * 400);
            for (int k = 0; k < 100; ++k) {
                float4 w4 = wp[k];
                const int kk = k * 4;
                a0 += w4.x*rs[0][kk] + w4.y*rs[0][kk+1] + w4.z*rs[0][kk+2] + w4.w*rs[0][kk+3];
                a1 += w4.x*rs[1][kk] + w4.y*rs[1][kk+1] + w4.z*rs[1][kk+2] + w4.w*rs[1][kk+3];
                a2 += w4.x*rs[2][kk] + w4.y*rs[2][kk+1] + w4.z*rs[2][kk+2] + w4.w*rs[2][kk+3];
                a3 += w4.x*rs[3][kk] + w4.y*rs[3][kk+1] + w4.z*rs[3][kk+2] + w4.w*rs[3][kk+3];
            }
            const float bb = bl[j];
            code[(size_t)(b0+0)*400 + j] = a0 + bb;
            code[(size_t)(b0+1)*400 + j] = a1 + bb;
            code[(size_t)(b0+2)*400 + j] = a2 + bb;
            code[(size_t)(b0+3)*400 + j] = a3 + bb;
        }
    }
}

// ---------------- K2: layer0 GRU: tile=8, 8 waves, 256 blocks, one barrier/step.
// Pair-row remap (batch 2q+i at h_bf row 4q+i) -> lane-local gates.
// code_s reads hoisted: 8 contiguous floats per batch per 4-step chunk
// loaded as 2x b128 (4 ds_read_b32/step -> 1 amortized). Same f32 values,
// bit-identical math. h_st rows padded to 136.
__global__ __launch_bounds__(512, 2) void k_gru0(
    const float* __restrict__ code,
    const float* __restrict__ Wih_f, const float* __restrict__ Whh_f,
    const float* __restrict__ bih_f, const float* __restrict__ bhh_f,
    const float* __restrict__ Wih_b, const float* __restrict__ Whh_b,
    const float* __restrict__ bih_b, const float* __restrict__ bhh_b,
    __bf16* __restrict__ h0) {
    const int dir = blockIdx.y;
    const int b0 = blockIdx.x * 8;
    const float* Wih = dir ? Wih_b : Wih_f;
    const float* Whh = dir ? Whh_b : Whh_f;
    const float* bih = dir ? bih_b : bih_f;
    const float* bhh = dir ? bhh_b : bhh_f;

    const int tid = threadIdx.x;
    const int w = tid >> 6, ln = tid & 63, q = ln >> 4, r16 = ln & 15;
    const int jj = w * 16 + r16;   // this wave's 16 output columns

    __shared__ __bf16 h_bf[2][16][136];      //  8,704 B (batch rows {4q+i}, rest zero)
    __shared__ float  code_s[8][400];        // 12,800 B
    __shared__ __bf16 h_st[2][8][8][136];    // 34,816 B stage, rows padded +8

    for (int i = tid; i < 8 * 400; i += 512) ((float*)code_s)[i] = code[(size_t)b0 * 400 + i];
    for (int i = tid; i < 2 * 16 * 136; i += 512) ((__bf16*)h_bf)[i] = (__bf16)0.f;

    bf16x8 wfr[3][4];
    const float wr0 = Wih[jj * 2],         wr1 = Wih[jj * 2 + 1];
    const float wz0 = Wih[(jj + 128) * 2], wz1 = Wih[(jj + 128) * 2 + 1];
    const float wn0 = Wih[(jj + 256) * 2], wn1 = Wih[(jj + 256) * 2 + 1];
    const float xbr = bih[jj] + bhh[jj];
    const float xbz = bih[jj + 128] + bhh[jj + 128];
    const float xbn = bih[jj + 256];
    const float bnv = bhh[jj + 256];
    float hreg2[2] = {0.f, 0.f};
    #pragma unroll
    for (int g = 0; g < 3; ++g) {
        const int j = (w + g * 8) * 16 + r16;
        const float* p = Whh + (size_t)j * H_;
        #pragma unroll
        for (int kt = 0; kt < 4; ++kt) {
            float4 x0 = *(const float4*)(p + kt * 32 + q * 8);
            float4 x1 = *(const float4*)(p + kt * 32 + q * 8 + 4);
            wfr[g][kt] = cvt8(x0, x1);
        }
    }
    __syncthreads();

    for (int c = 0; c < 50; ++c) {
        // ---- chunk preload: 8 contiguous floats of code per batch row
        // (dir=0: floats [8c..8c+7]; dir=1: floats [392-8c..399-8c])
        float4 cr[2][2];
        {
            const int base = dir ? (392 - 8 * c) : (8 * c);
            #pragma unroll
            for (int i = 0; i < 2; ++i) {
                const float4* cp = (const float4*)&code_s[2 * q + i][base];
                cr[i][0] = cp[0];
                cr[i][1] = cp[1];
            }
        }
        #pragma unroll
        for (int s = 0; s < 4; ++s) {
            const int t = c * 4 + s;
            const int cur = s & 1, nxt = cur ^ 1;
            // flush previous 8-step group (stores retire during following steps)
            if (s == 0 && (c & 1) == 0 && c > 0) {
                const int g8 = (c >> 1) - 1;
                const int buf = g8 & 1;
                const int p = tid >> 3, inner = tid & 7;     // 64 pairs x 8 threads
                const int ss = p >> 3, row = p & 7;
                const int tb = g8 * 8 + ss;
                const int lf = dir ? (L_ - 1 - tb) : tb;
                const __bf16* src = &h_st[buf][ss][row][inner * 16];
                __bf16* dst = &h0[((size_t)(b0 + row) * L_ + lf) * 256 + dir * 128 + inner * 16];
                *(bf16x8*)(dst)     = *(const bf16x8*)(src);
                *(bf16x8*)(dst + 8) = *(const bf16x8*)(src + 8);
            }
            bf16x8 af[4];
            #pragma unroll
            for (int kt = 0; kt < 4; ++kt)
                af[kt] = *(const bf16x8*)&h_bf[cur][r16][kt * 32 + q * 8];

            f32x4 ar = {0.f,0.f,0.f,0.f}, az = {0.f,0.f,0.f,0.f}, an = {0.f,0.f,0.f,0.f};
            #pragma unroll
            for (int kt = 0; kt < 4; ++kt) {
                ar = __builtin_amdgcn_mfma_f32_16x16x32_bf16(af[kt], wfr[0][kt], ar, 0, 0, 0);
                az = __builtin_amdgcn_mfma_f32_16x16x32_bf16(af[kt], wfr[1][kt], az, 0, 0, 0);
                an = __builtin_amdgcn_mfma_f32_16x16x32_bf16(af[kt], wfr[2][kt], an, 0, 0, 0);
            }
            // lane-local: batch 2q+i at C row 4q+i -> reg i; code from registers
            #pragma unroll
            for (int i = 0; i < 2; ++i) {
                const int m = 2 * q + i;
                // step s uses float pair (2s,2s+1) fwd or (6-2s,7-2s) bwd
                const int e0 = dir ? (6 - 2 * s) : (2 * s);
                const float c0 = (e0 < 4) ? ((const float*)&cr[i][0])[e0 & 3]
                                          : ((const float*)&cr[i][1])[e0 & 3];
                const float c1 = ((e0 + 1) < 4) ? ((const float*)&cr[i][0])[(e0 + 1) & 3]
                                                : ((const float*)&cr[i][1])[(e0 + 1) & 3];
                const float r = sigf(c0 * wr0 + c1 * wr1 + xbr + ar[i]);
                const float z = sigf(c0 * wz0 + c1 * wz1 + xbz + az[i]);
                const float n = tanh_fast(c0 * wn0 + c1 * wn1 + xbn + r * (an[i] + bnv));
                const float hv = n + z * (hreg2[i] - n);
                hreg2[i] = hv;
                h_bf[nxt][4 * q + i][jj] = (__bf16)hv;
                h_st[(t >> 3) & 1][t & 7][m][jj] = (__bf16)hv;
            }
            barrier_lds();   // single barrier: h[nxt] + stage visible (LDS only)
        }
    }
    {   // final flush: group 24 (t=192..199), buf = 24&1 = 0
        const int p = tid >> 3, inner = tid & 7;
        const int s = p >> 3, row = p & 7;
        const int tb = 192 + s;
        const int lf = dir ? (L_ - 1 - tb) : tb;
        const __bf16* src = &h_st[0][s][row][inner * 16];
        __bf16* dst = &h0[((size_t)(b0 + row) * L_ + lf) * 256 + dir * 128 + inner * 16];
        *(bf16x8*)(dst)     = *(const bf16x8*)(src);
        *(bf16x8*)(dst + 8) = *(const bf16x8*)(src + 8);
    }
}

// ---------------- K3: convert Wih1 (both dirs) fp32 -> bf16  [2][384][256]
__global__ __launch_bounds__(256) void k_cvtW(
    const float* __restrict__ Wfp, const float* __restrict__ Wbp,
    __bf16* __restrict__ out) {
    const int j = blockIdx.x * 256 + threadIdx.x;
    const int base = j * 4;
    const int dir = base >= 98304;
    const int idx = dir ? base - 98304 : base;
    float4 v = *(const float4*)((dir ? Wbp : Wfp) + idx);
    bf16x4 o;
    o[0] = (__bf16)v.x; o[1] = (__bf16)v.y; o[2] = (__bf16)v.z; o[3] = (__bf16)v.w;
    *(bf16x4*)&out[base] = o;
}

// ---------------- K4: layer1 GRU — xg in registers, fully lane-local gates,
// DPP final-linear reduce; wacc transposed to [par][m][w] so the tid<8
// readback is 2x b128 instead of 8x b32 (same sum order, bit-identical).
__global__ __launch_bounds__(512, 2) void k_gru1f(
    const __bf16* __restrict__ h0,       // [B][L][256]
    const __bf16* __restrict__ Wihbf,    // [2][384][256] bf16
    const float* __restrict__ bih_f, const float* __restrict__ bhh_f,
    const float* __restrict__ bih_b, const float* __restrict__ bhh_b,
    const float* __restrict__ Whh_f, const float* __restrict__ Whh_b,
    const float* __restrict__ Wfin,
    float* __restrict__ partial) {
    const int dir = blockIdx.y;
    const int b0 = blockIdx.x * 8;
    const float* Whh = dir ? Whh_b : Whh_f;
    const float* bih = dir ? bih_b : bih_f;
    const float* bhh = dir ? bhh_b : bhh_f;
    const __bf16* Wb = Wihbf + (size_t)dir * 384 * 256;

    const int tid = threadIdx.x;
    const int w = tid >> 6, ln = tid & 63, q = ln >> 4, r16 = ln & 15;
    const int jj = w * 16 + r16;   // this wave's 16 recurrence columns

    __shared__ __bf16 xa[2][32][264];    // 33,792 B  A-chunk dbuf (remapped rows)
    __shared__ __bf16 h_bf[2][16][136];  //  8,704 B  (batch rows {4q+i}, rest zero)
    __shared__ float  wacc[2][8][8];     //    512 B  [par][m][w]

    for (int i = tid; i < 2 * 16 * 136; i += 512) ((__bf16*)h_bf)[i] = (__bf16)0.f;

    bf16x8 wfr[3][4];
    bf16x8 wB[3][8];                      // register-resident Wih1 B-frags
    const float xbr = bih[jj] + bhh[jj];
    const float xbz = bih[jj + 128] + bhh[jj + 128];
    const float xbn = bih[jj + 256];
    const float bnv = bhh[jj + 256];
    const float wfv = Wfin[dir * 128 + jj];
    float hreg2[2] = {0.f, 0.f};
    #pragma unroll
    for (int g = 0; g < 3; ++g) {
        const int j = (w + g * 8) * 16 + r16;
        const float* p = Whh + (size_t)j * H_;
        #pragma unroll
        for (int kt = 0; kt < 4; ++kt) {
            float4 x0 = *(const float4*)(p + kt * 32 + q * 8);
            float4 x1 = *(const float4*)(p + kt * 32 + q * 8 + 4);
            wfr[g][kt] = cvt8(x0, x1);
        }
    }
    #pragma unroll
    for (int n = 0; n < 3; ++n) {
        const int ct = w + n * 8;        // tile ct -> cols jj + n*128
        const __bf16* wp = Wb + (size_t)(ct * 16 + r16) * 256 + q * 8;
        #pragma unroll
        for (int k8 = 0; k8 < 8; ++k8)
            wB[n][k8] = *(const bf16x8*)(wp + k8 * 32);
    }
    // xa row decode for staging threads: r = 16*mt + 4*a + 2*sh + b
    const int prr = tid >> 4, prs = tid & 15;     // 32 rows x 16 segs
    const int pmt = prr >> 4, pr4 = prr & 15;
    const int pa = pr4 >> 2, psh = (pr4 >> 1) & 1, pb = pr4 & 1;
    const int pS = 2 * pmt + psh;                  // step within chunk
    const int pBt = 2 * pa + pb;                   // batch
    // prologue: stage chunk 0 into xa[0]
    {
        const int l = dir ? (L_ - 1 - pS) : pS;    // t = pS
        const __bf16* src = h0 + ((size_t)(b0 + pBt) * L_ + l) * 256 + prs * 16;
        *(bf16x8*)&xa[0][prr][prs * 16]     = *(const bf16x8*)(src);
        *(bf16x8*)&xa[0][prr][prs * 16 + 8] = *(const bf16x8*)(src + 8);
    }
    __syncthreads();

    for (int c = 0; c < 50; ++c) {
        const int cb = c & 1, nb = cb ^ 1;
        // ---- issue prefetch loads for chunk c+1 (hidden under GEMM + 3 steps)
        bf16x8 pf0, pf1;
        const bool pv = (c + 1 < 50);
        if (pv) {
            const int t = (c + 1) * 4 + pS;
            const int l = dir ? (L_ - 1 - t) : t;
            const __bf16* src = h0 + ((size_t)(b0 + pBt) * L_ + l) * 256 + prs * 16;
            pf0 = *(const bf16x8*)(src);
            pf1 = *(const bf16x8*)(src + 8);
        }

        // ---- chunk GEMM into persistent registers: C row 16*mt + 4q + reg
        // = xg[batch 2q + (reg&1)][step 2*mt + (reg>>1)][col jj + n*128]
        f32x4 accg[3][2];
        #pragma unroll
        for (int n = 0; n < 3; ++n)
            #pragma unroll
            for (int mt = 0; mt < 2; ++mt) {
                accg[n][mt][0]=0.f; accg[n][mt][1]=0.f;
                accg[n][mt][2]=0.f; accg[n][mt][3]=0.f;
            }
        #pragma unroll
        for (int k8 = 0; k8 < 8; ++k8) {
            const bf16x8 a0 = *(const bf16x8*)&xa[cb][r16][k8 * 32 + q * 8];
            const bf16x8 a1 = *(const bf16x8*)&xa[cb][16 + r16][k8 * 32 + q * 8];
            #pragma unroll
            for (int n = 0; n < 3; ++n) {
                accg[n][0] = __builtin_amdgcn_mfma_f32_16x16x32_bf16(a0, wB[n][k8], accg[n][0], 0, 0, 0);
                accg[n][1] = __builtin_amdgcn_mfma_f32_16x16x32_bf16(a1, wB[n][k8], accg[n][1], 0, 0, 0);
            }
        }

        // ---- 4 recurrent steps, one barrier each
        #pragma unroll
        for (int s = 0; s < 4; ++s) {
            const int cur = s & 1, nxt = cur ^ 1;   // gstep = 4c+s, 4c even
            const int par = s & 1;
            const int t = c * 4 + s;
            const int l = dir ? (L_ - 1 - t) : t;
            const int mt = s >> 1;

            bf16x8 af[4];
            #pragma unroll
            for (int kt = 0; kt < 4; ++kt)
                af[kt] = *(const bf16x8*)&h_bf[cur][r16][kt * 32 + q * 8];

            f32x4 ar = {0.f,0.f,0.f,0.f}, az = {0.f,0.f,0.f,0.f}, an = {0.f,0.f,0.f,0.f};
            #pragma unroll
            for (int kt = 0; kt < 4; ++kt) {
                ar = __builtin_amdgcn_mfma_f32_16x16x32_bf16(af[kt], wfr[0][kt], ar, 0, 0, 0);
                az = __builtin_amdgcn_mfma_f32_16x16x32_bf16(af[kt], wfr[1][kt], az, 0, 0, 0);
                an = __builtin_amdgcn_mfma_f32_16x16x32_bf16(af[kt], wfr[2][kt], an, 0, 0, 0);
            }

            float hv2[2];
            #pragma unroll
            for (int i = 0; i < 2; ++i) {
                const int reg = 2 * (s & 1) + i;      // xg reg for batch 2q+i, step s
                const float xrv = accg[0][mt][reg];
                const float xzv = accg[1][mt][reg];
                const float xnv = accg[2][mt][reg];
                const float r = sigf(xrv + xbr + ar[i]);
                const float z = sigf(xzv + xbz + az[i]);
                const float n = tanh_fast(xnv + xbn + r * (an[i] + bnv));
                const float hv = n + z * (hreg2[i] - n);
                hreg2[i] = hv;
                hv2[i] = hv;
                h_bf[nxt][4 * q + i][jj] = (__bf16)hv;
            }
            // fused final-linear partial dot: DPP 16-lane sum (VALU, no DS ops)
            #pragma unroll
            for (int i = 0; i < 2; ++i) {
                const float v = red16(hv2[i] * wfv);
                if (r16 == 0) wacc[par][2 * q + i][w] = v;
            }
            // park prefetched chunk c+1 into xa[nb]; published by this barrier
            if (pv && s == 2) {
                *(bf16x8*)&xa[nb][prr][prs * 16]     = pf0;
                *(bf16x8*)&xa[nb][prr][prs * 16 + 8] = pf1;
            }
            barrier_lds();   // h[nxt] + wacc[par] (+ xa park) visible; no vmcnt drain
            if (tid < 8) {     // vectorized readback: 2x b128, same sum order
                const float4 u0 = *(const float4*)&wacc[par][tid][0];
                const float4 u1 = *(const float4*)&wacc[par][tid][4];
                float v = 0.f;
                v += u0.x; v += u0.y; v += u0.z; v += u0.w;
                v += u1.x; v += u1.y; v += u1.z; v += u1.w;
                partial[(size_t)dir * BL_ + (size_t)(b0 + tid) * L_ + l] = v;
            }
        }
    }
}

// ---------------- K5: out = sigmoid(pf + pb + bf)
__global__ __launch_bounds__(256) void k_final(
    const float* __restrict__ partial, const float* __restrict__ bfp,
    float* __restrict__ out) {
    const int i = blockIdx.x * 256 + threadIdx.x;
    if (i < BL_) out[i] = sigf(partial[i] + partial[BL_ + i] + bfp[0]);
}

extern "C" void kernel_launch(void* const* d_in, const int* in_sizes, int n_in,
                              void* d_out, int out_size, void* d_ws, size_t ws_size,
                              hipStream_t stream) {
    const float* rcv   = (const float*)d_in[0];
    const float* Wl    = (const float*)d_in[1];
    const float* bl    = (const float*)d_in[2];
    const float* Wih0f = (const float*)d_in[3];
    const float* Whh0f = (const float*)d_in[4];
    const float* bih0f = (const float*)d_in[5];
    const float* bhh0f = (const float*)d_in[6];
    const float* Wih0b = (const float*)d_in[7];
    const float* Whh0b = (const float*)d_in[8];
    const float* bih0b = (const float*)d_in[9];
    const float* bhh0b = (const float*)d_in[10];
    const float* Wih1f = (const float*)d_in[11];
    const float* Whh1f = (const float*)d_in[12];
    const float* bih1f = (const float*)d_in[13];
    const float* bhh1f = (const float*)d_in[14];
    const float* Wih1b = (const float*)d_in[15];
    const float* Whh1b = (const float*)d_in[16];
    const float* bih1b = (const float*)d_in[17];
    const float* bhh1b = (const float*)d_in[18];
    const float* Wfin  = (const float*)d_in[19];
    const float* bfin  = (const float*)d_in[20];

    const size_t OFF_CODE = 0;                     // 1,638,400 B
    const size_t OFF_PART = 1638400;               // 1,638,400 B
    const size_t OFF_H0   = 3276800;               // 104,857,600 B
    const size_t OFF_WBF  = 108134400;             //     393,216 B
    const size_t WS_NEEDED = 108527616;            // ~103.5 MB total

    if (ws_size < WS_NEEDED) {
        k_sentinel<<<(out_size + 255) / 256, 256, 0, stream>>>((float*)d_out, out_size);
        return;
    }

    char* ws = (char*)d_ws;
    float*  code    = (float*)(ws + OFF_CODE);
    float*  partial = (float*)(ws + OFF_PART);
    __bf16* h0      = (__bf16*)(ws + OFF_H0);
    __bf16* Wihbf   = (__bf16*)(ws + OFF_WBF);

    k_declin<<<256, 256, 0, stream>>>(rcv, Wl, bl, code);
    k_cvtW<<<192, 256, 0, stream>>>(Wih1f, Wih1b, Wihbf);
    k_gru0<<<dim3(128, 2), 512, 0, stream>>>(code, Wih0f, Whh0f, bih0f, bhh0f,
                                             Wih0b, Whh0b, bih0b, bhh0b, h0);
    k_gru1f<<<dim3(128, 2), 512, 0, stream>>>(h0, Wihbf,
                                              bih1f, bhh1f, bih1b, bhh1b,
                                              Whh1f, Whh1b, Wfin, partial);
    k_final<<<800, 256, 0, stream>>>(partial, bfin, (float*)d_out);
}

// Round 10
// 403.702 us; speedup vs baseline: 1.1044x; 1.1044x over previous
//
#include <hip/hip_runtime.h>
#include <hip/hip_bf16.h>

#define B_   1024
#define L_   200
#define H_   128
#define BL_  204800   // B_*L_
#define G3_  384

typedef __bf16 bf16x8 __attribute__((ext_vector_type(8)));
typedef __bf16 bf16x4 __attribute__((ext_vector_type(4)));
typedef float  f32x4  __attribute__((ext_vector_type(4)));

__device__ __forceinline__ float sigf(float x) {
    return __builtin_amdgcn_rcpf(1.f + __expf(-x));
}
__device__ __forceinline__ float tanh_fast(float x) {
    float e = __expf(-2.f * x);
    return (1.f - e) * __builtin_amdgcn_rcpf(1.f + e);
}
__device__ __forceinline__ bf16x8 cvt8(float4 a, float4 b) {
    bf16x8 v;
    v[0] = (__bf16)a.x; v[1] = (__bf16)a.y; v[2] = (__bf16)a.z; v[3] = (__bf16)a.w;
    v[4] = (__bf16)b.x; v[5] = (__bf16)b.y; v[6] = (__bf16)b.z; v[7] = (__bf16)b.w;
    return v;
}
// LDS-only barrier: waits ds-ops (lgkmcnt) but does NOT drain vmcnt — global
// prefetch loads / result stores stay in flight across steps.
__device__ __forceinline__ void barrier_lds() {
    __builtin_amdgcn_sched_barrier(0);
    asm volatile("s_waitcnt lgkmcnt(0)" ::: "memory");
    __builtin_amdgcn_s_barrier();
    __builtin_amdgcn_sched_barrier(0);
}
// 16-lane sum via DPP row_ror adds (VALU pipe) — all lanes get the sum.
__device__ __forceinline__ float red16(float v) {
    v += __int_as_float(__builtin_amdgcn_update_dpp(0, __float_as_int(v), 0x121, 0xF, 0xF, true)); // ror:1
    v += __int_as_float(__builtin_amdgcn_update_dpp(0, __float_as_int(v), 0x122, 0xF, 0xF, true)); // ror:2
    v += __int_as_float(__builtin_amdgcn_update_dpp(0, __float_as_int(v), 0x124, 0xF, 0xF, true)); // ror:4
    v += __int_as_float(__builtin_amdgcn_update_dpp(0, __float_as_int(v), 0x128, 0xF, 0xF, true)); // ror:8
    return v;
}

// ---------------- K0: sentinel (workspace too small -> distinguishable absmax)
__global__ __launch_bounds__(256) void k_sentinel(float* __restrict__ out, int n) {
    const int i = blockIdx.x * 256 + threadIdx.x;
    if (i < n) out[i] = -5.0f;
}

// ---------------- K1: dec_linear
__global__ __launch_bounds__(256) void k_declin(
    const float* __restrict__ rcv, const float* __restrict__ Wl,
    const float* __restrict__ bl, float* __restrict__ code) {
    __shared__ float rs[4][400];
    const int tid = threadIdx.x;
    const int b0 = blockIdx.x * 4;
    for (int i = tid; i < 1600; i += 256) ((float*)rs)[i] = rcv[(size_t)b0 * 400 + i];
    __syncthreads();
    #pragma unroll
    for (int rep = 0; rep < 2; ++rep) {
        const int j = tid + rep * 256;
        if (j < 400) {
            float a0 = 0.f, a1 = 0.f, a2 = 0.f, a3 = 0.f;
            const float4* wp = (const float4*)(Wl + (size_t)j * 400);
            for (int k = 0; k < 100; ++k) {
                float4 w4 = wp[k];
                const int kk = k * 4;
                a0 += w4.x*rs[0][kk] + w4.y*rs[0][kk+1] + w4.z*rs[0][kk+2] + w4.w*rs[0][kk+3];
                a1 += w4.x*rs[1][kk] + w4.y*rs[1][kk+1] + w4.z*rs[1][kk+2] + w4.w*rs[1][kk+3];
                a2 += w4.x*rs[2][kk] + w4.y*rs[2][kk+1] + w4.z*rs[2][kk+2] + w4.w*rs[2][kk+3];
                a3 += w4.x*rs[3][kk] + w4.y*rs[3][kk+1] + w4.z*rs[3][kk+2] + w4.w*rs[3][kk+3];
            }
            const float bb = bl[j];
            code[(size_t)(b0+0)*400 + j] = a0 + bb;
            code[(size_t)(b0+1)*400 + j] = a1 + bb;
            code[(size_t)(b0+2)*400 + j] = a2 + bb;
            code[(size_t)(b0+3)*400 + j] = a3 + bb;
        }
    }
}

// ---------------- K2: layer0 GRU: tile=8, 8 waves, 256 blocks, one barrier/step.
// Pair-row remap (batch 2q+i at h_bf row 4q+i) -> lane-local gates.
// code operand now REGISTER-resident: chunk c's 8 floats/batch prefetched
// from global (float4), permuted once per chunk into cs[2][8] under a
// uniform dir-branch with ALL-CONSTANT indices (no scratch — rule #20).
// Removes 4 ds_read_b32/lane/step (-33% LDS instr budget). Same f32 values
// -> bit-identical math. h_st padded 136, lgkm-only barriers.
__global__ __launch_bounds__(512, 2) void k_gru0(
    const float* __restrict__ code,
    const float* __restrict__ Wih_f, const float* __restrict__ Whh_f,
    const float* __restrict__ bih_f, const float* __restrict__ bhh_f,
    const float* __restrict__ Wih_b, const float* __restrict__ Whh_b,
    const float* __restrict__ bih_b, const float* __restrict__ bhh_b,
    __bf16* __restrict__ h0) {
    const int dir = blockIdx.y;
    const int b0 = blockIdx.x * 8;
    const float* Wih = dir ? Wih_b : Wih_f;
    const float* Whh = dir ? Whh_b : Whh_f;
    const float* bih = dir ? bih_b : bih_f;
    const float* bhh = dir ? bhh_b : bhh_f;

    const int tid = threadIdx.x;
    const int w = tid >> 6, ln = tid & 63, q = ln >> 4, r16 = ln & 15;
    const int jj = w * 16 + r16;   // this wave's 16 output columns

    __shared__ __bf16 h_bf[2][16][136];      //  8,704 B (batch rows {4q+i}, rest zero)
    __shared__ __bf16 h_st[2][8][8][136];    // 34,816 B stage, rows padded +8

    for (int i = tid; i < 2 * 16 * 136; i += 512) ((__bf16*)h_bf)[i] = (__bf16)0.f;

    bf16x8 wfr[3][4];
    const float wr0 = Wih[jj * 2],         wr1 = Wih[jj * 2 + 1];
    const float wz0 = Wih[(jj + 128) * 2], wz1 = Wih[(jj + 128) * 2 + 1];
    const float wn0 = Wih[(jj + 256) * 2], wn1 = Wih[(jj + 256) * 2 + 1];
    const float xbr = bih[jj] + bhh[jj];
    const float xbz = bih[jj + 128] + bhh[jj + 128];
    const float xbn = bih[jj + 256];
    const float bnv = bhh[jj + 256];
    float hreg2[2] = {0.f, 0.f};
    #pragma unroll
    for (int g = 0; g < 3; ++g) {
        const int j = (w + g * 8) * 16 + r16;
        const float* p = Whh + (size_t)j * H_;
        #pragma unroll
        for (int kt = 0; kt < 4; ++kt) {
            float4 x0 = *(const float4*)(p + kt * 32 + q * 8);
            float4 x1 = *(const float4*)(p + kt * 32 + q * 8 + 4);
            wfr[g][kt] = cvt8(x0, x1);
        }
    }
    // code prefetch registers: bufA = current chunk, bufB = next chunk
    float4 bufA[4], bufB[4];
    {   // chunk 0: floats [0..7] fwd, [392..399] bwd
        const int base = dir ? 392 : 0;
        const float* cp0 = code + (size_t)(b0 + 2 * q) * 400 + base;
        const float* cp1 = code + (size_t)(b0 + 2 * q + 1) * 400 + base;
        bufA[0] = *(const float4*)(cp0);
        bufA[1] = *(const float4*)(cp0 + 4);
        bufA[2] = *(const float4*)(cp1);
        bufA[3] = *(const float4*)(cp1 + 4);
    }
    __syncthreads();

    for (int c = 0; c < 50; ++c) {
        // ---- issue prefetch for chunk c+1 (retires during this chunk's 4 steps)
        if (c + 1 < 50) {
            const int base = dir ? (392 - 8 * (c + 1)) : (8 * (c + 1));
            const float* cp0 = code + (size_t)(b0 + 2 * q) * 400 + base;
            const float* cp1 = code + (size_t)(b0 + 2 * q + 1) * 400 + base;
            bufB[0] = *(const float4*)(cp0);
            bufB[1] = *(const float4*)(cp0 + 4);
            bufB[2] = *(const float4*)(cp1);
            bufB[3] = *(const float4*)(cp1 + 4);
        }
        // ---- permute to step order, uniform branch, constant indices only:
        // step s uses cs[i][2s], cs[i][2s+1] = code pair (2s,2s+1) fwd / (6-2s,7-2s) bwd
        float cs[2][8];
        if (dir == 0) {
            cs[0][0]=bufA[0].x; cs[0][1]=bufA[0].y; cs[0][2]=bufA[0].z; cs[0][3]=bufA[0].w;
            cs[0][4]=bufA[1].x; cs[0][5]=bufA[1].y; cs[0][6]=bufA[1].z; cs[0][7]=bufA[1].w;
            cs[1][0]=bufA[2].x; cs[1][1]=bufA[2].y; cs[1][2]=bufA[2].z; cs[1][3]=bufA[2].w;
            cs[1][4]=bufA[3].x; cs[1][5]=bufA[3].y; cs[1][6]=bufA[3].z; cs[1][7]=bufA[3].w;
        } else {
            cs[0][0]=bufA[1].z; cs[0][1]=bufA[1].w; cs[0][2]=bufA[1].x; cs[0][3]=bufA[1].y;
            cs[0][4]=bufA[0].z; cs[0][5]=bufA[0].w; cs[0][6]=bufA[0].x; cs[0][7]=bufA[0].y;
            cs[1][0]=bufA[3].z; cs[1][1]=bufA[3].w; cs[1][2]=bufA[3].x; cs[1][3]=bufA[3].y;
            cs[1][4]=bufA[2].z; cs[1][5]=bufA[2].w; cs[1][6]=bufA[2].x; cs[1][7]=bufA[2].y;
        }
        #pragma unroll
        for (int s = 0; s < 4; ++s) {
            const int t = c * 4 + s;
            const int cur = s & 1, nxt = cur ^ 1;   // t&1 == s&1
            // flush previous 8-step group (stores retire during following steps)
            if (s == 0 && (c & 1) == 0 && c > 0) {
                const int g8 = (c >> 1) - 1;
                const int buf = g8 & 1;
                const int p = tid >> 3, inner = tid & 7;     // 64 pairs x 8 threads
                const int ss = p >> 3, row = p & 7;
                const int tb = g8 * 8 + ss;
                const int lf = dir ? (L_ - 1 - tb) : tb;
                const __bf16* src = &h_st[buf][ss][row][inner * 16];
                __bf16* dst = &h0[((size_t)(b0 + row) * L_ + lf) * 256 + dir * 128 + inner * 16];
                *(bf16x8*)(dst)     = *(const bf16x8*)(src);
                *(bf16x8*)(dst + 8) = *(const bf16x8*)(src + 8);
            }
            bf16x8 af[4];
            #pragma unroll
            for (int kt = 0; kt < 4; ++kt)
                af[kt] = *(const bf16x8*)&h_bf[cur][r16][kt * 32 + q * 8];

            f32x4 ar = {0.f,0.f,0.f,0.f}, az = {0.f,0.f,0.f,0.f}, an = {0.f,0.f,0.f,0.f};
            #pragma unroll
            for (int kt = 0; kt < 4; ++kt) {
                ar = __builtin_amdgcn_mfma_f32_16x16x32_bf16(af[kt], wfr[0][kt], ar, 0, 0, 0);
                az = __builtin_amdgcn_mfma_f32_16x16x32_bf16(af[kt], wfr[1][kt], az, 0, 0, 0);
                an = __builtin_amdgcn_mfma_f32_16x16x32_bf16(af[kt], wfr[2][kt], an, 0, 0, 0);
            }
            // lane-local: batch 2q+i at C row 4q+i -> reg i; code from registers
            #pragma unroll
            for (int i = 0; i < 2; ++i) {
                const int m = 2 * q + i;
                const float c0 = cs[i][2 * s], c1 = cs[i][2 * s + 1];
                const float r = sigf(c0 * wr0 + c1 * wr1 + xbr + ar[i]);
                const float z = sigf(c0 * wz0 + c1 * wz1 + xbz + az[i]);
                const float n = tanh_fast(c0 * wn0 + c1 * wn1 + xbn + r * (an[i] + bnv));
                const float hv = n + z * (hreg2[i] - n);
                hreg2[i] = hv;
                h_bf[nxt][4 * q + i][jj] = (__bf16)hv;
                h_st[(t >> 3) & 1][t & 7][m][jj] = (__bf16)hv;
            }
            barrier_lds();   // single barrier: h[nxt] + stage visible (LDS only)
        }
        // ---- rotate prefetched chunk into bufA (register moves; compiler
        // inserts the vmcnt wait here, ~4 steps after issue)
        if (c + 1 < 50) {
            bufA[0] = bufB[0]; bufA[1] = bufB[1];
            bufA[2] = bufB[2]; bufA[3] = bufB[3];
        }
    }
    {   // final flush: group 24 (t=192..199), buf = 24&1 = 0
        const int p = tid >> 3, inner = tid & 7;
        const int s = p >> 3, row = p & 7;
        const int tb = 192 + s;
        const int lf = dir ? (L_ - 1 - tb) : tb;
        const __bf16* src = &h_st[0][s][row][inner * 16];
        __bf16* dst = &h0[((size_t)(b0 + row) * L_ + lf) * 256 + dir * 128 + inner * 16];
        *(bf16x8*)(dst)     = *(const bf16x8*)(src);
        *(bf16x8*)(dst + 8) = *(const bf16x8*)(src + 8);
    }
}

// ---------------- K3: convert Wih1 (both dirs) fp32 -> bf16  [2][384][256]
__global__ __launch_bounds__(256) void k_cvtW(
    const float* __restrict__ Wfp, const float* __restrict__ Wbp,
    __bf16* __restrict__ out) {
    const int j = blockIdx.x * 256 + threadIdx.x;
    const int base = j * 4;
    const int dir = base >= 98304;
    const int idx = dir ? base - 98304 : base;
    float4 v = *(const float4*)((dir ? Wbp : Wfp) + idx);
    bf16x4 o;
    o[0] = (__bf16)v.x; o[1] = (__bf16)v.y; o[2] = (__bf16)v.z; o[3] = (__bf16)v.w;
    *(bf16x4*)&out[base] = o;
}

// ---------------- K4: layer1 GRU — xg in registers, fully lane-local gates,
// DPP-based final-linear reduce (exact R6 state, 179.8 us proven).
__global__ __launch_bounds__(512, 2) void k_gru1f(
    const __bf16* __restrict__ h0,       // [B][L][256]
    const __bf16* __restrict__ Wihbf,    // [2][384][256] bf16
    const float* __restrict__ bih_f, const float* __restrict__ bhh_f,
    const float* __restrict__ bih_b, const float* __restrict__ bhh_b,
    const float* __restrict__ Whh_f, const float* __restrict__ Whh_b,
    const float* __restrict__ Wfin,
    float* __restrict__ partial) {
    const int dir = blockIdx.y;
    const int b0 = blockIdx.x * 8;
    const float* Whh = dir ? Whh_b : Whh_f;
    const float* bih = dir ? bih_b : bih_f;
    const float* bhh = dir ? bhh_b : bhh_f;
    const __bf16* Wb = Wihbf + (size_t)dir * 384 * 256;

    const int tid = threadIdx.x;
    const int w = tid >> 6, ln = tid & 63, q = ln >> 4, r16 = ln & 15;
    const int jj = w * 16 + r16;   // this wave's 16 recurrence columns

    __shared__ __bf16 xa[2][32][264];    // 33,792 B  A-chunk dbuf (remapped rows)
    __shared__ __bf16 h_bf[2][16][136];  //  8,704 B  (batch rows {4q+i}, rest zero)
    __shared__ float  wacc[2][8][8];     //    512 B

    for (int i = tid; i < 2 * 16 * 136; i += 512) ((__bf16*)h_bf)[i] = (__bf16)0.f;

    bf16x8 wfr[3][4];
    bf16x8 wB[3][8];                      // register-resident Wih1 B-frags
    const float xbr = bih[jj] + bhh[jj];
    const float xbz = bih[jj + 128] + bhh[jj + 128];
    const float xbn = bih[jj + 256];
    const float bnv = bhh[jj + 256];
    const float wfv = Wfin[dir * 128 + jj];
    float hreg2[2] = {0.f, 0.f};
    #pragma unroll
    for (int g = 0; g < 3; ++g) {
        const int j = (w + g * 8) * 16 + r16;
        const float* p = Whh + (size_t)j * H_;
        #pragma unroll
        for (int kt = 0; kt < 4; ++kt) {
            float4 x0 = *(const float4*)(p + kt * 32 + q * 8);
            float4 x1 = *(const float4*)(p + kt * 32 + q * 8 + 4);
            wfr[g][kt] = cvt8(x0, x1);
        }
    }
    #pragma unroll
    for (int n = 0; n < 3; ++n) {
        const int ct = w + n * 8;        // tile ct -> cols jj + n*128
        const __bf16* wp = Wb + (size_t)(ct * 16 + r16) * 256 + q * 8;
        #pragma unroll
        for (int k8 = 0; k8 < 8; ++k8)
            wB[n][k8] = *(const bf16x8*)(wp + k8 * 32);
    }
    // xa row decode for staging threads: r = 16*mt + 4*a + 2*sh + b
    const int prr = tid >> 4, prs = tid & 15;     // 32 rows x 16 segs
    const int pmt = prr >> 4, pr4 = prr & 15;
    const int pa = pr4 >> 2, psh = (pr4 >> 1) & 1, pb = pr4 & 1;
    const int pS = 2 * pmt + psh;                  // step within chunk
    const int pBt = 2 * pa + pb;                   // batch
    // prologue: stage chunk 0 into xa[0]
    {
        const int l = dir ? (L_ - 1 - pS) : pS;    // t = pS
        const __bf16* src = h0 + ((size_t)(b0 + pBt) * L_ + l) * 256 + prs * 16;
        *(bf16x8*)&xa[0][prr][prs * 16]     = *(const bf16x8*)(src);
        *(bf16x8*)&xa[0][prr][prs * 16 + 8] = *(const bf16x8*)(src + 8);
    }
    __syncthreads();

    for (int c = 0; c < 50; ++c) {
        const int cb = c & 1, nb = cb ^ 1;
        // ---- issue prefetch loads for chunk c+1 (hidden under GEMM + 3 steps)
        bf16x8 pf0, pf1;
        const bool pv = (c + 1 < 50);
        if (pv) {
            const int t = (c + 1) * 4 + pS;
            const int l = dir ? (L_ - 1 - t) : t;
            const __bf16* src = h0 + ((size_t)(b0 + pBt) * L_ + l) * 256 + prs * 16;
            pf0 = *(const bf16x8*)(src);
            pf1 = *(const bf16x8*)(src + 8);
        }

        // ---- chunk GEMM into persistent registers: C row 16*mt + 4q + reg
        // = xg[batch 2q + (reg&1)][step 2*mt + (reg>>1)][col jj + n*128]
        f32x4 accg[3][2];
        #pragma unroll
        for (int n = 0; n < 3; ++n)
            #pragma unroll
            for (int mt = 0; mt < 2; ++mt) {
                accg[n][mt][0]=0.f; accg[n][mt][1]=0.f;
                accg[n][mt][2]=0.f; accg[n][mt][3]=0.f;
            }
        #pragma unroll
        for (int k8 = 0; k8 < 8; ++k8) {
            const bf16x8 a0 = *(const bf16x8*)&xa[cb][r16][k8 * 32 + q * 8];
            const bf16x8 a1 = *(const bf16x8*)&xa[cb][16 + r16][k8 * 32 + q * 8];
            #pragma unroll
            for (int n = 0; n < 3; ++n) {
                accg[n][0] = __builtin_amdgcn_mfma_f32_16x16x32_bf16(a0, wB[n][k8], accg[n][0], 0, 0, 0);
                accg[n][1] = __builtin_amdgcn_mfma_f32_16x16x32_bf16(a1, wB[n][k8], accg[n][1], 0, 0, 0);
            }
        }

        // ---- 4 recurrent steps, one barrier each
        #pragma unroll
        for (int s = 0; s < 4; ++s) {
            const int cur = s & 1, nxt = cur ^ 1;   // gstep = 4c+s, 4c even
            const int par = s & 1;
            const int t = c * 4 + s;
            const int l = dir ? (L_ - 1 - t) : t;
            const int mt = s >> 1;

            bf16x8 af[4];
            #pragma unroll
            for (int kt = 0; kt < 4; ++kt)
                af[kt] = *(const bf16x8*)&h_bf[cur][r16][kt * 32 + q * 8];

            f32x4 ar = {0.f,0.f,0.f,0.f}, az = {0.f,0.f,0.f,0.f}, an = {0.f,0.f,0.f,0.f};
            #pragma unroll
            for (int kt = 0; kt < 4; ++kt) {
                ar = __builtin_amdgcn_mfma_f32_16x16x32_bf16(af[kt], wfr[0][kt], ar, 0, 0, 0);
                az = __builtin_amdgcn_mfma_f32_16x16x32_bf16(af[kt], wfr[1][kt], az, 0, 0, 0);
                an = __builtin_amdgcn_mfma_f32_16x16x32_bf16(af[kt], wfr[2][kt], an, 0, 0, 0);
            }

            float hv2[2];
            #pragma unroll
            for (int i = 0; i < 2; ++i) {
                const int reg = 2 * (s & 1) + i;      // xg reg for batch 2q+i, step s
                const float xrv = accg[0][mt][reg];
                const float xzv = accg[1][mt][reg];
                const float xnv = accg[2][mt][reg];
                const float r = sigf(xrv + xbr + ar[i]);
                const float z = sigf(xzv + xbz + az[i]);
                const float n = tanh_fast(xnv + xbn + r * (an[i] + bnv));
                const float hv = n + z * (hreg2[i] - n);
                hreg2[i] = hv;
                hv2[i] = hv;
                h_bf[nxt][4 * q + i][jj] = (__bf16)hv;
            }
            // fused final-linear partial dot: DPP 16-lane sum (VALU, no DS ops)
            #pragma unroll
            for (int i = 0; i < 2; ++i) {
                const float v = red16(hv2[i] * wfv);
                if (r16 == 0) wacc[par][w][2 * q + i] = v;
            }
            // park prefetched chunk c+1 into xa[nb]; published by this barrier
            if (pv && s == 2) {
                *(bf16x8*)&xa[nb][prr][prs * 16]     = pf0;
                *(bf16x8*)&xa[nb][prr][prs * 16 + 8] = pf1;
            }
            barrier_lds();   // h[nxt] + wacc[par] (+ xa park) visible; no vmcnt drain
            if (tid < 8) {     // tiny store, drains lazily over following steps
                float v = 0.f;
                #pragma unroll
                for (int ww = 0; ww < 8; ++ww) v += wacc[par][ww][tid];
                partial[(size_t)dir * BL_ + (size_t)(b0 + tid) * L_ + l] = v;
            }
        }
    }
}

// ---------------- K5: out = sigmoid(pf + pb + bf)
__global__ __launch_bounds__(256) void k_final(
    const float* __restrict__ partial, const float* __restrict__ bfp,
    float* __restrict__ out) {
    const int i = blockIdx.x * 256 + threadIdx.x;
    if (i < BL_) out[i] = sigf(partial[i] + partial[BL_ + i] + bfp[0]);
}

extern "C" void kernel_launch(void* const* d_in, const int* in_sizes, int n_in,
                              void* d_out, int out_size, void* d_ws, size_t ws_size,
                              hipStream_t stream) {
    const float* rcv   = (const float*)d_in[0];
    const float* Wl    = (const float*)d_in[1];
    const float* bl    = (const float*)d_in[2];
    const float* Wih0f = (const float*)d_in[3];
    const float* Whh0f = (const float*)d_in[4];
    const float* bih0f = (const float*)d_in[5];
    const float* bhh0f = (const float*)d_in[6];
    const float* Wih0b = (const float*)d_in[7];
    const float* Whh0b = (const float*)d_in[8];
    const float* bih0b = (const float*)d_in[9];
    const float* bhh0b = (const float*)d_in[10];
    const float* Wih1f = (const float*)d_in[11];
    const float* Whh1f = (const float*)d_in[12];
    const float* bih1f = (const float*)d_in[13];
    const float* bhh1f = (const float*)d_in[14];
    const float* Wih1b = (const float*)d_in[15];
    const float* Whh1b = (const float*)d_in[16];
    const float* bih1b = (const float*)d_in[17];
    const float* bhh1b = (const float*)d_in[18];
    const float* Wfin  = (const float*)d_in[19];
    const float* bfin  = (const float*)d_in[20];

    const size_t OFF_CODE = 0;                     // 1,638,400 B
    const size_t OFF_PART = 1638400;               // 1,638,400 B
    const size_t OFF_H0   = 3276800;               // 104,857,600 B
    const size_t OFF_WBF  = 108134400;             //     393,216 B
    const size_t WS_NEEDED = 108527616;            // ~103.5 MB total

    if (ws_size < WS_NEEDED) {
        k_sentinel<<<(out_size + 255) / 256, 256, 0, stream>>>((float*)d_out, out_size);
        return;
    }

    char* ws = (char*)d_ws;
    float*  code    = (float*)(ws + OFF_CODE);
    float*  partial = (float*)(ws + OFF_PART);
    __bf16* h0      = (__bf16*)(ws + OFF_H0);
    __bf16* Wihbf   = (__bf16*)(ws + OFF_WBF);

    k_declin<<<256, 256, 0, stream>>>(rcv, Wl, bl, code);
    k_cvtW<<<192, 256, 0, stream>>>(Wih1f, Wih1b, Wihbf);
    k_gru0<<<dim3(128, 2), 512, 0, stream>>>(code, Wih0f, Whh0f, bih0f, bhh0f,
                                             Wih0b, Whh0b, bih0b, bhh0b, h0);
    k_gru1f<<<dim3(128, 2), 512, 0, stream>>>(h0, Wihbf,
                                              bih1f, bhh1f, bih1b, bhh1b,
                                              Whh1f, Whh1b, Wfin, partial);
    k_final<<<800, 256, 0, stream>>>(partial, bfin, (float*)d_out);
}

// Round 11
// 394.906 us; speedup vs baseline: 1.1290x; 1.0223x over previous
//
#include <hip/hip_runtime.h>
#include <hip/hip_bf16.h>

#define B_   1024
#define L_   200
#define H_   128
#define BL_  204800   // B_*L_
#define G3_  384

typedef __bf16 bf16x8 __attribute__((ext_vector_type(8)));
typedef __bf16 bf16x4 __attribute__((ext_vector_type(4)));
typedef float  f32x4  __attribute__((ext_vector_type(4)));

__device__ __forceinline__ float sigf(float x) {
    return __builtin_amdgcn_rcpf(1.f + __expf(-x));
}
__device__ __forceinline__ float tanh_fast(float x) {
    float e = __expf(-2.f * x);
    return (1.f - e) * __builtin_amdgcn_rcpf(1.f + e);
}
__device__ __forceinline__ bf16x8 cvt8(float4 a, float4 b) {
    bf16x8 v;
    v[0] = (__bf16)a.x; v[1] = (__bf16)a.y; v[2] = (__bf16)a.z; v[3] = (__bf16)a.w;
    v[4] = (__bf16)b.x; v[5] = (__bf16)b.y; v[6] = (__bf16)b.z; v[7] = (__bf16)b.w;
    return v;
}
// LDS-only barrier: waits ds-ops (lgkmcnt) but does NOT drain vmcnt — global
// prefetch loads / result stores stay in flight across steps.
__device__ __forceinline__ void barrier_lds() {
    __builtin_amdgcn_sched_barrier(0);
    asm volatile("s_waitcnt lgkmcnt(0)" ::: "memory");
    __builtin_amdgcn_s_barrier();
    __builtin_amdgcn_sched_barrier(0);
}
// 16-lane sum via DPP row_ror adds (VALU pipe) — all lanes get the sum.
__device__ __forceinline__ float red16(float v) {
    v += __int_as_float(__builtin_amdgcn_update_dpp(0, __float_as_int(v), 0x121, 0xF, 0xF, true)); // ror:1
    v += __int_as_float(__builtin_amdgcn_update_dpp(0, __float_as_int(v), 0x122, 0xF, 0xF, true)); // ror:2
    v += __int_as_float(__builtin_amdgcn_update_dpp(0, __float_as_int(v), 0x124, 0xF, 0xF, true)); // ror:4
    v += __int_as_float(__builtin_amdgcn_update_dpp(0, __float_as_int(v), 0x128, 0xF, 0xF, true)); // ror:8
    return v;
}

// ---------------- K0: sentinel (workspace too small -> distinguishable absmax)
__global__ __launch_bounds__(256) void k_sentinel(float* __restrict__ out, int n) {
    const int i = blockIdx.x * 256 + threadIdx.x;
    if (i < n) out[i] = -5.0f;
}

// ---------------- K1: dec_linear — batch tile 2, grid 512 -> 2 blocks/CU
// (2 waves/SIMD latency hiding vs 1 before). Same per-output k-order ->
// bit-identical results.
__global__ __launch_bounds__(256) void k_declin(
    const float* __restrict__ rcv, const float* __restrict__ Wl,
    const float* __restrict__ bl, float* __restrict__ code) {
    __shared__ float rs[2][400];
    const int tid = threadIdx.x;
    const int b0 = blockIdx.x * 2;
    for (int i = tid; i < 800; i += 256) ((float*)rs)[i] = rcv[(size_t)b0 * 400 + i];
    __syncthreads();
    #pragma unroll
    for (int rep = 0; rep < 2; ++rep) {
        const int j = tid + rep * 256;
        if (j < 400) {
            float a0 = 0.f, a1 = 0.f;
            const float4* wp = (const float4*)(Wl + (size_t)j * 400);
            for (int k = 0; k < 100; ++k) {
                float4 w4 = wp[k];
                const int kk = k * 4;
                a0 += w4.x*rs[0][kk] + w4.y*rs[0][kk+1] + w4.z*rs[0][kk+2] + w4.w*rs[0][kk+3];
                a1 += w4.x*rs[1][kk] + w4.y*rs[1][kk+1] + w4.z*rs[1][kk+2] + w4.w*rs[1][kk+3];
            }
            const float bb = bl[j];
            code[(size_t)(b0+0)*400 + j] = a0 + bb;
            code[(size_t)(b0+1)*400 + j] = a1 + bb;
        }
    }
}

// ---------------- K2: layer0 GRU: tile=8, 8 waves, 256 blocks, one barrier/step.
// Pair-row remap (batch 2q+i at h_bf row 4q+i) -> lane-local gates.
// code operand REGISTER-resident (global float4 prefetch, uniform dir-branch
// permute, all-constant indices). h_st padded 136, lgkm-only barriers.
__global__ __launch_bounds__(512, 2) void k_gru0(
    const float* __restrict__ code,
    const float* __restrict__ Wih_f, const float* __restrict__ Whh_f,
    const float* __restrict__ bih_f, const float* __restrict__ bhh_f,
    const float* __restrict__ Wih_b, const float* __restrict__ Whh_b,
    const float* __restrict__ bih_b, const float* __restrict__ bhh_b,
    __bf16* __restrict__ h0) {
    const int dir = blockIdx.y;
    const int b0 = blockIdx.x * 8;
    const float* Wih = dir ? Wih_b : Wih_f;
    const float* Whh = dir ? Whh_b : Whh_f;
    const float* bih = dir ? bih_b : bih_f;
    const float* bhh = dir ? bhh_b : bhh_f;

    const int tid = threadIdx.x;
    const int w = tid >> 6, ln = tid & 63, q = ln >> 4, r16 = ln & 15;
    const int jj = w * 16 + r16;   // this wave's 16 output columns

    __shared__ __bf16 h_bf[2][16][136];      //  8,704 B (batch rows {4q+i}, rest zero)
    __shared__ __bf16 h_st[2][8][8][136];    // 34,816 B stage, rows padded +8

    for (int i = tid; i < 2 * 16 * 136; i += 512) ((__bf16*)h_bf)[i] = (__bf16)0.f;

    bf16x8 wfr[3][4];
    const float wr0 = Wih[jj * 2],         wr1 = Wih[jj * 2 + 1];
    const float wz0 = Wih[(jj + 128) * 2], wz1 = Wih[(jj + 128) * 2 + 1];
    const float wn0 = Wih[(jj + 256) * 2], wn1 = Wih[(jj + 256) * 2 + 1];
    const float xbr = bih[jj] + bhh[jj];
    const float xbz = bih[jj + 128] + bhh[jj + 128];
    const float xbn = bih[jj + 256];
    const float bnv = bhh[jj + 256];
    float hreg2[2] = {0.f, 0.f};
    #pragma unroll
    for (int g = 0; g < 3; ++g) {
        const int j = (w + g * 8) * 16 + r16;
        const float* p = Whh + (size_t)j * H_;
        #pragma unroll
        for (int kt = 0; kt < 4; ++kt) {
            float4 x0 = *(const float4*)(p + kt * 32 + q * 8);
            float4 x1 = *(const float4*)(p + kt * 32 + q * 8 + 4);
            wfr[g][kt] = cvt8(x0, x1);
        }
    }
    // code prefetch registers: bufA = current chunk, bufB = next chunk
    float4 bufA[4], bufB[4];
    {   // chunk 0: floats [0..7] fwd, [392..399] bwd
        const int base = dir ? 392 : 0;
        const float* cp0 = code + (size_t)(b0 + 2 * q) * 400 + base;
        const float* cp1 = code + (size_t)(b0 + 2 * q + 1) * 400 + base;
        bufA[0] = *(const float4*)(cp0);
        bufA[1] = *(const float4*)(cp0 + 4);
        bufA[2] = *(const float4*)(cp1);
        bufA[3] = *(const float4*)(cp1 + 4);
    }
    __syncthreads();

    for (int c = 0; c < 50; ++c) {
        // ---- issue prefetch for chunk c+1 (retires during this chunk's 4 steps)
        if (c + 1 < 50) {
            const int base = dir ? (392 - 8 * (c + 1)) : (8 * (c + 1));
            const float* cp0 = code + (size_t)(b0 + 2 * q) * 400 + base;
            const float* cp1 = code + (size_t)(b0 + 2 * q + 1) * 400 + base;
            bufB[0] = *(const float4*)(cp0);
            bufB[1] = *(const float4*)(cp0 + 4);
            bufB[2] = *(const float4*)(cp1);
            bufB[3] = *(const float4*)(cp1 + 4);
        }
        // ---- permute to step order, uniform branch, constant indices only:
        // step s uses cs[i][2s], cs[i][2s+1] = code pair (2s,2s+1) fwd / (6-2s,7-2s) bwd
        float cs[2][8];
        if (dir == 0) {
            cs[0][0]=bufA[0].x; cs[0][1]=bufA[0].y; cs[0][2]=bufA[0].z; cs[0][3]=bufA[0].w;
            cs[0][4]=bufA[1].x; cs[0][5]=bufA[1].y; cs[0][6]=bufA[1].z; cs[0][7]=bufA[1].w;
            cs[1][0]=bufA[2].x; cs[1][1]=bufA[2].y; cs[1][2]=bufA[2].z; cs[1][3]=bufA[2].w;
            cs[1][4]=bufA[3].x; cs[1][5]=bufA[3].y; cs[1][6]=bufA[3].z; cs[1][7]=bufA[3].w;
        } else {
            cs[0][0]=bufA[1].z; cs[0][1]=bufA[1].w; cs[0][2]=bufA[1].x; cs[0][3]=bufA[1].y;
            cs[0][4]=bufA[0].z; cs[0][5]=bufA[0].w; cs[0][6]=bufA[0].x; cs[0][7]=bufA[0].y;
            cs[1][0]=bufA[3].z; cs[1][1]=bufA[3].w; cs[1][2]=bufA[3].x; cs[1][3]=bufA[3].y;
            cs[1][4]=bufA[2].z; cs[1][5]=bufA[2].w; cs[1][6]=bufA[2].x; cs[1][7]=bufA[2].y;
        }
        #pragma unroll
        for (int s = 0; s < 4; ++s) {
            const int t = c * 4 + s;
            const int cur = s & 1, nxt = cur ^ 1;   // t&1 == s&1
            // flush previous 8-step group (stores retire during following steps)
            if (s == 0 && (c & 1) == 0 && c > 0) {
                const int g8 = (c >> 1) - 1;
                const int buf = g8 & 1;
                const int p = tid >> 3, inner = tid & 7;     // 64 pairs x 8 threads
                const int ss = p >> 3, row = p & 7;
                const int tb = g8 * 8 + ss;
                const int lf = dir ? (L_ - 1 - tb) : tb;
                const __bf16* src = &h_st[buf][ss][row][inner * 16];
                __bf16* dst = &h0[((size_t)(b0 + row) * L_ + lf) * 256 + dir * 128 + inner * 16];
                *(bf16x8*)(dst)     = *(const bf16x8*)(src);
                *(bf16x8*)(dst + 8) = *(const bf16x8*)(src + 8);
            }
            bf16x8 af[4];
            #pragma unroll
            for (int kt = 0; kt < 4; ++kt)
                af[kt] = *(const bf16x8*)&h_bf[cur][r16][kt * 32 + q * 8];

            f32x4 ar = {0.f,0.f,0.f,0.f}, az = {0.f,0.f,0.f,0.f}, an = {0.f,0.f,0.f,0.f};
            #pragma unroll
            for (int kt = 0; kt < 4; ++kt) {
                ar = __builtin_amdgcn_mfma_f32_16x16x32_bf16(af[kt], wfr[0][kt], ar, 0, 0, 0);
                az = __builtin_amdgcn_mfma_f32_16x16x32_bf16(af[kt], wfr[1][kt], az, 0, 0, 0);
                an = __builtin_amdgcn_mfma_f32_16x16x32_bf16(af[kt], wfr[2][kt], an, 0, 0, 0);
            }
            // lane-local: batch 2q+i at C row 4q+i -> reg i; code from registers
            #pragma unroll
            for (int i = 0; i < 2; ++i) {
                const int m = 2 * q + i;
                const float c0 = cs[i][2 * s], c1 = cs[i][2 * s + 1];
                const float r = sigf(c0 * wr0 + c1 * wr1 + xbr + ar[i]);
                const float z = sigf(c0 * wz0 + c1 * wz1 + xbz + az[i]);
                const float n = tanh_fast(c0 * wn0 + c1 * wn1 + xbn + r * (an[i] + bnv));
                const float hv = n + z * (hreg2[i] - n);
                hreg2[i] = hv;
                h_bf[nxt][4 * q + i][jj] = (__bf16)hv;
                h_st[(t >> 3) & 1][t & 7][m][jj] = (__bf16)hv;
            }
            barrier_lds();   // single barrier: h[nxt] + stage visible (LDS only)
        }
        // ---- rotate prefetched chunk into bufA (register moves; compiler
        // inserts the vmcnt wait here, ~4 steps after issue)
        if (c + 1 < 50) {
            bufA[0] = bufB[0]; bufA[1] = bufB[1];
            bufA[2] = bufB[2]; bufA[3] = bufB[3];
        }
    }
    {   // final flush: group 24 (t=192..199), buf = 24&1 = 0
        const int p = tid >> 3, inner = tid & 7;
        const int s = p >> 3, row = p & 7;
        const int tb = 192 + s;
        const int lf = dir ? (L_ - 1 - tb) : tb;
        const __bf16* src = &h_st[0][s][row][inner * 16];
        __bf16* dst = &h0[((size_t)(b0 + row) * L_ + lf) * 256 + dir * 128 + inner * 16];
        *(bf16x8*)(dst)     = *(const bf16x8*)(src);
        *(bf16x8*)(dst + 8) = *(const bf16x8*)(src + 8);
    }
}

// ---------------- K3: convert Wih1 (both dirs) fp32 -> bf16  [2][384][256]
__global__ __launch_bounds__(256) void k_cvtW(
    const float* __restrict__ Wfp, const float* __restrict__ Wbp,
    __bf16* __restrict__ out) {
    const int j = blockIdx.x * 256 + threadIdx.x;
    const int base = j * 4;
    const int dir = base >= 98304;
    const int idx = dir ? base - 98304 : base;
    float4 v = *(const float4*)((dir ? Wbp : Wfp) + idx);
    bf16x4 o;
    o[0] = (__bf16)v.x; o[1] = (__bf16)v.y; o[2] = (__bf16)v.z; o[3] = (__bf16)v.w;
    *(bf16x4*)&out[base] = o;
}

// ---------------- K4: layer1 GRU — xg in registers, fully lane-local gates,
// DPP-based final-linear reduce (proven 179.0 us state).
__global__ __launch_bounds__(512, 2) void k_gru1f(
    const __bf16* __restrict__ h0,       // [B][L][256]
    const __bf16* __restrict__ Wihbf,    // [2][384][256] bf16
    const float* __restrict__ bih_f, const float* __restrict__ bhh_f,
    const float* __restrict__ bih_b, const float* __restrict__ bhh_b,
    const float* __restrict__ Whh_f, const float* __restrict__ Whh_b,
    const float* __restrict__ Wfin,
    float* __restrict__ partial) {
    const int dir = blockIdx.y;
    const int b0 = blockIdx.x * 8;
    const float* Whh = dir ? Whh_b : Whh_f;
    const float* bih = dir ? bih_b : bih_f;
    const float* bhh = dir ? bhh_b : bhh_f;
    const __bf16* Wb = Wihbf + (size_t)dir * 384 * 256;

    const int tid = threadIdx.x;
    const int w = tid >> 6, ln = tid & 63, q = ln >> 4, r16 = ln & 15;
    const int jj = w * 16 + r16;   // this wave's 16 recurrence columns

    __shared__ __bf16 xa[2][32][264];    // 33,792 B  A-chunk dbuf (remapped rows)
    __shared__ __bf16 h_bf[2][16][136];  //  8,704 B  (batch rows {4q+i}, rest zero)
    __shared__ float  wacc[2][8][8];     //    512 B

    for (int i = tid; i < 2 * 16 * 136; i += 512) ((__bf16*)h_bf)[i] = (__bf16)0.f;

    bf16x8 wfr[3][4];
    bf16x8 wB[3][8];                      // register-resident Wih1 B-frags
    const float xbr = bih[jj] + bhh[jj];
    const float xbz = bih[jj + 128] + bhh[jj + 128];
    const float xbn = bih[jj + 256];
    const float bnv = bhh[jj + 256];
    const float wfv = Wfin[dir * 128 + jj];
    float hreg2[2] = {0.f, 0.f};
    #pragma unroll
    for (int g = 0; g < 3; ++g) {
        const int j = (w + g * 8) * 16 + r16;
        const float* p = Whh + (size_t)j * H_;
        #pragma unroll
        for (int kt = 0; kt < 4; ++kt) {
            float4 x0 = *(const float4*)(p + kt * 32 + q * 8);
            float4 x1 = *(const float4*)(p + kt * 32 + q * 8 + 4);
            wfr[g][kt] = cvt8(x0, x1);
        }
    }
    #pragma unroll
    for (int n = 0; n < 3; ++n) {
        const int ct = w + n * 8;        // tile ct -> cols jj + n*128
        const __bf16* wp = Wb + (size_t)(ct * 16 + r16) * 256 + q * 8;
        #pragma unroll
        for (int k8 = 0; k8 < 8; ++k8)
            wB[n][k8] = *(const bf16x8*)(wp + k8 * 32);
    }
    // xa row decode for staging threads: r = 16*mt + 4*a + 2*sh + b
    const int prr = tid >> 4, prs = tid & 15;     // 32 rows x 16 segs
    const int pmt = prr >> 4, pr4 = prr & 15;
    const int pa = pr4 >> 2, psh = (pr4 >> 1) & 1, pb = pr4 & 1;
    const int pS = 2 * pmt + psh;                  // step within chunk
    const int pBt = 2 * pa + pb;                   // batch
    // prologue: stage chunk 0 into xa[0]
    {
        const int l = dir ? (L_ - 1 - pS) : pS;    // t = pS
        const __bf16* src = h0 + ((size_t)(b0 + pBt) * L_ + l) * 256 + prs * 16;
        *(bf16x8*)&xa[0][prr][prs * 16]     = *(const bf16x8*)(src);
        *(bf16x8*)&xa[0][prr][prs * 16 + 8] = *(const bf16x8*)(src + 8);
    }
    __syncthreads();

    for (int c = 0; c < 50; ++c) {
        const int cb = c & 1, nb = cb ^ 1;
        // ---- issue prefetch loads for chunk c+1 (hidden under GEMM + 3 steps)
        bf16x8 pf0, pf1;
        const bool pv = (c + 1 < 50);
        if (pv) {
            const int t = (c + 1) * 4 + pS;
            const int l = dir ? (L_ - 1 - t) : t;
            const __bf16* src = h0 + ((size_t)(b0 + pBt) * L_ + l) * 256 + prs * 16;
            pf0 = *(const bf16x8*)(src);
            pf1 = *(const bf16x8*)(src + 8);
        }

        // ---- chunk GEMM into persistent registers: C row 16*mt + 4q + reg
        // = xg[batch 2q + (reg&1)][step 2*mt + (reg>>1)][col jj + n*128]
        f32x4 accg[3][2];
        #pragma unroll
        for (int n = 0; n < 3; ++n)
            #pragma unroll
            for (int mt = 0; mt < 2; ++mt) {
                accg[n][mt][0]=0.f; accg[n][mt][1]=0.f;
                accg[n][mt][2]=0.f; accg[n][mt][3]=0.f;
            }
        #pragma unroll
        for (int k8 = 0; k8 < 8; ++k8) {
            const bf16x8 a0 = *(const bf16x8*)&xa[cb][r16][k8 * 32 + q * 8];
            const bf16x8 a1 = *(const bf16x8*)&xa[cb][16 + r16][k8 * 32 + q * 8];
            #pragma unroll
            for (int n = 0; n < 3; ++n) {
                accg[n][0] = __builtin_amdgcn_mfma_f32_16x16x32_bf16(a0, wB[n][k8], accg[n][0], 0, 0, 0);
                accg[n][1] = __builtin_amdgcn_mfma_f32_16x16x32_bf16(a1, wB[n][k8], accg[n][1], 0, 0, 0);
            }
        }

        // ---- 4 recurrent steps, one barrier each
        #pragma unroll
        for (int s = 0; s < 4; ++s) {
            const int cur = s & 1, nxt = cur ^ 1;   // gstep = 4c+s, 4c even
            const int par = s & 1;
            const int t = c * 4 + s;
            const int l = dir ? (L_ - 1 - t) : t;
            const int mt = s >> 1;

            bf16x8 af[4];
            #pragma unroll
            for (int kt = 0; kt < 4; ++kt)
                af[kt] = *(const bf16x8*)&h_bf[cur][r16][kt * 32 + q * 8];

            f32x4 ar = {0.f,0.f,0.f,0.f}, az = {0.f,0.f,0.f,0.f}, an = {0.f,0.f,0.f,0.f};
            #pragma unroll
            for (int kt = 0; kt < 4; ++kt) {
                ar = __builtin_amdgcn_mfma_f32_16x16x32_bf16(af[kt], wfr[0][kt], ar, 0, 0, 0);
                az = __builtin_amdgcn_mfma_f32_16x16x32_bf16(af[kt], wfr[1][kt], az, 0, 0, 0);
                an = __builtin_amdgcn_mfma_f32_16x16x32_bf16(af[kt], wfr[2][kt], an, 0, 0, 0);
            }

            float hv2[2];
            #pragma unroll
            for (int i = 0; i < 2; ++i) {
                const int reg = 2 * (s & 1) + i;      // xg reg for batch 2q+i, step s
                const float xrv = accg[0][mt][reg];
                const float xzv = accg[1][mt][reg];
                const float xnv = accg[2][mt][reg];
                const float r = sigf(xrv + xbr + ar[i]);
                const float z = sigf(xzv + xbz + az[i]);
                const float n = tanh_fast(xnv + xbn + r * (an[i] + bnv));
                const float hv = n + z * (hreg2[i] - n);
                hreg2[i] = hv;
                hv2[i] = hv;
                h_bf[nxt][4 * q + i][jj] = (__bf16)hv;
            }
            // fused final-linear partial dot: DPP 16-lane sum (VALU, no DS ops)
            #pragma unroll
            for (int i = 0; i < 2; ++i) {
                const float v = red16(hv2[i] * wfv);
                if (r16 == 0) wacc[par][w][2 * q + i] = v;
            }
            // park prefetched chunk c+1 into xa[nb]; published by this barrier
            if (pv && s == 2) {
                *(bf16x8*)&xa[nb][prr][prs * 16]     = pf0;
                *(bf16x8*)&xa[nb][prr][prs * 16 + 8] = pf1;
            }
            barrier_lds();   // h[nxt] + wacc[par] (+ xa park) visible; no vmcnt drain
            if (tid < 8) {     // tiny store, drains lazily over following steps
                float v = 0.f;
                #pragma unroll
                for (int ww = 0; ww < 8; ++ww) v += wacc[par][ww][tid];
                partial[(size_t)dir * BL_ + (size_t)(b0 + tid) * L_ + l] = v;
            }
        }
    }
}

// ---------------- K5: out = sigmoid(pf + pb + bf)
__global__ __launch_bounds__(256) void k_final(
    const float* __restrict__ partial, const float* __restrict__ bfp,
    float* __restrict__ out) {
    const int i = blockIdx.x * 256 + threadIdx.x;
    if (i < BL_) out[i] = sigf(partial[i] + partial[BL_ + i] + bfp[0]);
}

extern "C" void kernel_launch(void* const* d_in, const int* in_sizes, int n_in,
                              void* d_out, int out_size, void* d_ws, size_t ws_size,
                              hipStream_t stream) {
    const float* rcv   = (const float*)d_in[0];
    const float* Wl    = (const float*)d_in[1];
    const float* bl    = (const float*)d_in[2];
    const float* Wih0f = (const float*)d_in[3];
    const float* Whh0f = (const float*)d_in[4];
    const float* bih0f = (const float*)d_in[5];
    const float* bhh0f = (const float*)d_in[6];
    const float* Wih0b = (const float*)d_in[7];
    const float* Whh0b = (const float*)d_in[8];
    const float* bih0b = (const float*)d_in[9];
    const float* bhh0b = (const float*)d_in[10];
    const float* Wih1f = (const float*)d_in[11];
    const float* Whh1f = (const float*)d_in[12];
    const float* bih1f = (const float*)d_in[13];
    const float* bhh1f = (const float*)d_in[14];
    const float* Wih1b = (const float*)d_in[15];
    const float* Whh1b = (const float*)d_in[16];
    const float* bih1b = (const float*)d_in[17];
    const float* bhh1b = (const float*)d_in[18];
    const float* Wfin  = (const float*)d_in[19];
    const float* bfin  = (const float*)d_in[20];

    const size_t OFF_CODE = 0;                     // 1,638,400 B
    const size_t OFF_PART = 1638400;               // 1,638,400 B
    const size_t OFF_H0   = 3276800;               // 104,857,600 B
    const size_t OFF_WBF  = 108134400;             //     393,216 B
    const size_t WS_NEEDED = 108527616;            // ~103.5 MB total

    if (ws_size < WS_NEEDED) {
        k_sentinel<<<(out_size + 255) / 256, 256, 0, stream>>>((float*)d_out, out_size);
        return;
    }

    char* ws = (char*)d_ws;
    float*  code    = (float*)(ws + OFF_CODE);
    float*  partial = (float*)(ws + OFF_PART);
    __bf16* h0      = (__bf16*)(ws + OFF_H0);
    __bf16* Wihbf   = (__bf16*)(ws + OFF_WBF);

    k_declin<<<512, 256, 0, stream>>>(rcv, Wl, bl, code);
    k_cvtW<<<192, 256, 0, stream>>>(Wih1f, Wih1b, Wihbf);
    k_gru0<<<dim3(128, 2), 512, 0, stream>>>(code, Wih0f, Whh0f, bih0f, bhh0f,
                                             Wih0b, Whh0b, bih0b, bhh0b, h0);
    k_gru1f<<<dim3(128, 2), 512, 0, stream>>>(h0, Wihbf,
                                              bih1f, bhh1f, bih1b, bhh1b,
                                              Whh1f, Whh1b, Wfin, partial);
    k_final<<<800, 256, 0, stream>>>(partial, bfin, (float*)d_out);
}